// Round 22
// baseline (310.951 us; speedup 1.0000x reference)
//
#include <hip/hip_runtime.h>
#include <hip/hip_bf16.h>
#include <math.h>

// ---------------------------------------------------------------------------
// GAT_E_to_R: N=100000, E=500000, EH=256, RH=128, R=1000
//   out[r] = y_h[r]@r_h_w + b_h + y_h[r] + y_t[r]@r_t_w + b_t + y_t[r],
//   y_s[r] = sum_e alpha_e * x_r_s[node_e]   (softmax weights sum to 1).
// k_fused: r14 champion + fused relation histogram + fused scan (last block).
// k_scatter: single int4 record (h,e1,t,e2), exp(logit) precomputed.
// k_rel: 512 thr / 8 slots, 4-deep gather ILP, no max pass.
// ---------------------------------------------------------------------------

#define EHD 256
#define RHD 128
#define RMAX 1024
#define HBLK 128    // blocks participating in fused histogram
#define SCHUNK 2048 // edges per scatter block
#define SEGMAX 4096 // max cached segment length in k_rel

typedef __attribute__((ext_vector_type(8))) short short8;
typedef __attribute__((ext_vector_type(4))) float f32x4;

__device__ __forceinline__ short f2bf(float x) {
    __hip_bfloat16 b = __float2bfloat16(x);   // RNE
    return *reinterpret_cast<short*>(&b);
}
__device__ __forceinline__ float bfu(unsigned int u) {
    return __uint_as_float(u << 16);
}
__device__ __forceinline__ float leaky(float x) { return x > 0.f ? x : 0.01f * x; }
// Xs swizzle: XOR 16B chunk index with row&7 (keeps short8 alignment)
__device__ __forceinline__ int xswz(int row, int col) {
    return col ^ ((row & 7) << 3);
}

// ---- transpose+convert both weight mats: dst[n][k] = src[k][n] (bf16) ------
__global__ __launch_bounds__(256) void k_prep2(const float* __restrict__ wh,
                                               const float* __restrict__ wt,
                                               short* __restrict__ whT,
                                               short* __restrict__ wtT)
{
    const float* src = blockIdx.z ? wt : wh;
    short* dst = blockIdx.z ? wtT : whT;
    __shared__ float t[32][33];
    const int k0 = blockIdx.x * 32, n0 = blockIdx.y * 32;
    const int tr = threadIdx.x >> 3, tc = (threadIdx.x & 7) << 2;
    float4 v = *reinterpret_cast<const float4*>(src + (size_t)(k0 + tr) * RHD + n0 + tc);
    t[tr][tc + 0] = v.x; t[tr][tc + 1] = v.y;
    t[tr][tc + 2] = v.z; t[tr][tc + 3] = v.w;
    __syncthreads();
    short* o = dst + (size_t)(n0 + tr) * EHD + k0 + tc;
    o[0] = f2bf(t[tc + 0][tr]); o[1] = f2bf(t[tc + 1][tr]);
    o[2] = f2bf(t[tc + 2][tr]); o[3] = f2bf(t[tc + 3][tr]);
}

// ---- fused: xr = xe@{wh,wt}; sA/sB; histogram; last block does the scan -----
__global__ __launch_bounds__(256, 4) void k_fused(
    const float* __restrict__ xe,
    const short* __restrict__ whT, const short* __restrict__ wtT,   // [128][256]
    const float* __restrict__ ah1, const float* __restrict__ ah2,
    const float* __restrict__ at1, const float* __restrict__ at2,
    float2* __restrict__ sA, float2* __restrict__ sB,
    short* __restrict__ xrh, short* __restrict__ xrt, int N,
    const int* __restrict__ rel, int* __restrict__ counts,
    int* __restrict__ starts, int* __restrict__ cursor,
    int* __restrict__ donecnt, int R, int E)
{
    __shared__ __align__(16) union {
        short Bs[2][2][128][32];       // 32 KB — [buf][mat][row][k] (unpadded)
        short Xs[2][64][128];          // 32 KB — epilogue transpose (swizzled)
        int   Hs[RMAX];                //  4 KB — fused histogram (tail)
        int   Sc[2][RMAX];             //  8 KB — fused scan buffers
    } u;
    __shared__ int lastflag;

    const int tid = threadIdx.x;
    const int w = tid >> 6, l = tid & 63;
    const int ln = l & 15, lk = l >> 4;
    const int m0 = blockIdx.x * 64;
    const int orow = (w << 4) + (lk << 2);

    f32x4 acch[8], acct[8];
#pragma unroll
    for (int c = 0; c < 8; c++) {
        acch[c] = (f32x4){0.f, 0.f, 0.f, 0.f};
        acct[c] = (f32x4){0.f, 0.f, 0.f, 0.f};
    }

    // -------- GEMM1: K=256, 8 k-steps --------
    const int arow = m0 + (w << 4) + ln;
    const int aclamp = min(arow, N - 1);
    const float* abase = xe + (size_t)aclamp * EHD + (lk << 3);
    short* BsFlat = &u.Bs[0][0][0][0];

    const int Rl = l >> 2, kc = l & 3;

    auto stage = [&](int buf, int kt) {
#pragma unroll
        for (int i = 0; i < 4; i++) {
            const int j = (w << 2) + i;            // 0..15 (uniform per wave)
            const int Rr = (j << 4) + Rl;          // 0..255
            const int mat = Rr >> 7, row = Rr & 127;
            const short* g = (mat ? wtT : whT) + (size_t)row * EHD + kt + (kc << 3);
            __builtin_amdgcn_global_load_lds(
                (const __attribute__((address_space(1))) void*)g,
                (__attribute__((address_space(3))) void*)(BsFlat + (buf << 13) + (j << 9)),
                16, 0, 0);
        }
    };

    float4 a0 = *reinterpret_cast<const float4*>(abase);
    float4 a1 = *reinterpret_cast<const float4*>(abase + 4);
    stage(0, 0);                       // prologue: fill buffer 0

#pragma unroll
    for (int s = 0; s < 8; s++) {
        const int kt = s << 5;
        __syncthreads();               // buf[s&1] staged (vmcnt drained) +
                                       // buf[(s+1)&1] reads from s-1 done
        if (s < 7) stage((s + 1) & 1, kt + 32);   // in flight over MFMA phase
        short8 af;
        af[0] = f2bf(a0.x); af[1] = f2bf(a0.y); af[2] = f2bf(a0.z); af[3] = f2bf(a0.w);
        af[4] = f2bf(a1.x); af[5] = f2bf(a1.y); af[6] = f2bf(a1.z); af[7] = f2bf(a1.w);
        if (s < 7) {                   // A reg-prefetch for next step
            a0 = *reinterpret_cast<const float4*>(abase + kt + 32);
            a1 = *reinterpret_cast<const float4*>(abase + kt + 36);
        }
        const int b = s & 1;
#pragma unroll
        for (int c = 0; c < 8; c++) {
            short8 bh = *reinterpret_cast<const short8*>(&u.Bs[b][0][(c << 4) + ln][lk << 3]);
            short8 bt = *reinterpret_cast<const short8*>(&u.Bs[b][1][(c << 4) + ln][lk << 3]);
            acch[c] = __builtin_amdgcn_mfma_f32_16x16x32_bf16(af, bh, acch[c], 0, 0, 0);
            acct[c] = __builtin_amdgcn_mfma_f32_16x16x32_bf16(af, bt, acct[c], 0, 0, 0);
        }
    }
    __syncthreads();   // all Bs reads done before Xs overwrites (union)

    // -------- epilogue: scalars from fp32 acc; xr -> LDS bf16 (swizzled) -----
    float p1[4] = {0,0,0,0}, p2[4] = {0,0,0,0}, p3[4] = {0,0,0,0}, p4[4] = {0,0,0,0};
#pragma unroll
    for (int c = 0; c < 8; c++) {
        const int col = (c << 4) + ln;
        const float wa1 = ah1[col], wa2 = ah2[col], wa3 = at1[col], wa4 = at2[col];
#pragma unroll
        for (int r = 0; r < 4; r++) {
            const float vh = acch[c][r], vt = acct[c][r];
            p1[r] = fmaf(vh, wa1, p1[r]);
            p3[r] = fmaf(vh, wa3, p3[r]);
            p2[r] = fmaf(vt, wa2, p2[r]);
            p4[r] = fmaf(vt, wa4, p4[r]);
            const int row = orow + r;
            const int cs = xswz(row, col);
            u.Xs[0][row][cs] = f2bf(vh);
            u.Xs[1][row][cs] = f2bf(vt);
        }
    }
#pragma unroll
    for (int off = 1; off < 16; off <<= 1) {
#pragma unroll
        for (int r = 0; r < 4; r++) {
            p1[r] += __shfl_xor(p1[r], off);
            p2[r] += __shfl_xor(p2[r], off);
            p3[r] += __shfl_xor(p3[r], off);
            p4[r] += __shfl_xor(p4[r], off);
        }
    }
    if (ln == 0) {
#pragma unroll
        for (int r = 0; r < 4; r++) {
            const int grow = m0 + orow + r;
            if (grow < N) {
                sA[grow] = make_float2(p1[r], p3[r]);
                sB[grow] = make_float2(p2[r], p4[r]);
            }
        }
    }
    __syncthreads();
    // coalesced short8 stores of x_r (2 mats x 64 rows x 16 chunks)
#pragma unroll
    for (int it = 0; it < 8; it++) {
        const int idx = tid + (it << 8);
        const int mat = idx >> 10;
        const int rem = idx & 1023;
        const int row = rem >> 4;
        const int ch  = rem & 15;
        const int grow = m0 + row;
        if (grow < N) {
            const int cs = (ch << 3) ^ ((row & 7) << 3);
            short8 v = *reinterpret_cast<const short8*>(&u.Xs[mat][row][cs]);
            short* dst = (mat ? xrt : xrh) + (size_t)grow * RHD + (ch << 3);
            *reinterpret_cast<short8*>(dst) = v;
        }
    }

    // -------- fused relation histogram (blocks 0..HBLK-1) --------------------
    if (blockIdx.x < HBLK) {
        __syncthreads();               // Xs reads above complete; reuse union
        for (int i = tid; i < R; i += 256) u.Hs[i] = 0;
        __syncthreads();
        for (int e = blockIdx.x * 256 + tid; e < E; e += HBLK * 256)
            atomicAdd(&u.Hs[rel[e]], 1);
        __syncthreads();
        for (int i = tid; i < R; i += 256) {
            int v = u.Hs[i];
            if (v) atomicAdd(&counts[i], v);
        }
    }

    // -------- fused scan: last block to finish scans counts -> starts/cursor -
    __threadfence();                   // order hist flush before counter bump
    if (tid == 0) {
        int prev = atomicAdd(donecnt, 1);
        lastflag = (prev == (int)gridDim.x - 1);
    }
    __syncthreads();
    if (lastflag) {
        __threadfence();               // acquire: see all blocks' counts
        __syncthreads();
        for (int i = tid; i < RMAX; i += 256)
            u.Sc[0][i] = (i < R) ? counts[i] : 0;
        __syncthreads();
        int cur = 0;
        for (int off = 1; off < RMAX; off <<= 1) {
            for (int i = tid; i < RMAX; i += 256) {
                int x = u.Sc[cur][i];
                if (i >= off) x += u.Sc[cur][i - off];
                u.Sc[cur ^ 1][i] = x;
            }
            __syncthreads();
            cur ^= 1;
        }
        for (int i = tid; i < R; i += 256) {
            const int st = u.Sc[cur][i] - counts[i];   // exclusive prefix
            starts[i] = st;
            cursor[i] = st;
        }
        if (tid == 0) starts[R] = E;
    }
}

// ---- block-privatized scatter into packed int4 records ----------------------
// rec[pos] = (h, exp(e1), t, exp(e2)) — one 16B store per edge.
__global__ __launch_bounds__(256) void k_scatter(
    const int* __restrict__ rel, int* __restrict__ cursor,
    const int* __restrict__ eh, const int* __restrict__ et,
    const float2* __restrict__ sA, const float2* __restrict__ sB,
    int4* __restrict__ rec, int R, int E)
{
    __shared__ int lcnt[RMAX];
    __shared__ int lbase[RMAX];
    const int tid = threadIdx.x;
    const int base = blockIdx.x * SCHUNK;
    const int nE = min(SCHUNK, E - base);
    for (int i = tid; i < R; i += 256) lcnt[i] = 0;
    __syncthreads();
    for (int i = tid; i < nE; i += 256) atomicAdd(&lcnt[rel[base + i]], 1);
    __syncthreads();
    for (int r = tid; r < R; r += 256) {
        int c = lcnt[r];
        lbase[r] = c ? atomicAdd(&cursor[r], c) : 0;
        lcnt[r] = 0;
    }
    __syncthreads();
    for (int i = tid; i < nE; i += 256) {
        const int e = base + i;
        const int r = rel[e];
        const int off = atomicAdd(&lcnt[r], 1);
        const int pos = lbase[r] + off;
        const int h = eh[e], t = et[e];
        const float2 va = sA[h];      // (s1[h], s3[h])
        const float2 vb = sB[t];      // (s2[t], s4[t])
        const float x1 = __expf(leaky(va.x + vb.x));   // bounded: |logit|<~10
        const float x2 = __expf(leaky(va.y + vb.y));
        rec[pos] = make_int4(h, __float_as_int(x1), t, __float_as_int(x2));
    }
}

// ---------------- per-(relation,side) normalize + weighted reduce into y ----
// records hold exp(logit); alpha = w / sum(w). 512 thr = 8 slots.
__global__ __launch_bounds__(512) void k_rel(
    const int* __restrict__ starts,
    const int4* __restrict__ rec,
    const short* __restrict__ xrh, const short* __restrict__ xrt,
    float* __restrict__ y, int R)   // y[2][R][128], pre-zeroed
{
    const int r = blockIdx.x;
    const int side = blockIdx.y;
    const int start = starts[r], end = starts[r + 1];
    const int len = end - start;
    if (len <= 0) return;                        // y pre-zeroed
    const int tid = threadIdx.x;
    const int4* __restrict__ rc = rec + start;
    const unsigned short* __restrict__ mb =
        reinterpret_cast<const unsigned short*>(side ? xrt : xrh);

    __shared__ float red[8];
    __shared__ int   lnode[SEGMAX];
    __shared__ float lal[SEGMAX];
    __shared__ float part[8][128];

    const int slot = tid >> 6;        // 0..7
    const int jj = tid & 63;
    float a0 = 0.f, a1 = 0.f;

    if (len <= SEGMAX) {
        float sum = 0.f;
        for (int i = tid; i < len; i += 512) {
            int4 v = rc[i];
            const int node = side ? v.z : v.x;
            const float x = __int_as_float(side ? v.w : v.y);
            lnode[i] = node;
            lal[i] = x;
            sum += x;
        }
#pragma unroll
        for (int off = 32; off > 0; off >>= 1) sum += __shfl_xor(sum, off);
        if ((tid & 63) == 0) red[slot] = sum;
        __syncthreads();
        sum = ((red[0] + red[1]) + (red[2] + red[3]))
            + ((red[4] + red[5]) + (red[6] + red[7]));
        const float inv = 1.f / sum;

        // accumulate: slot takes edges q = slot+8k; 4 gathers in flight
        int q = slot;
        for (; q + 24 < len; q += 32) {
            const float w0 = lal[q] * inv;       const int n0 = lnode[q];
            const float w1 = lal[q + 8] * inv;   const int n1 = lnode[q + 8];
            const float w2 = lal[q + 16] * inv;  const int n2 = lnode[q + 16];
            const float w3 = lal[q + 24] * inv;  const int n3 = lnode[q + 24];
            const unsigned int v0 =
                *reinterpret_cast<const unsigned int*>(mb + (size_t)n0 * RHD + (jj << 1));
            const unsigned int v1 =
                *reinterpret_cast<const unsigned int*>(mb + (size_t)n1 * RHD + (jj << 1));
            const unsigned int v2 =
                *reinterpret_cast<const unsigned int*>(mb + (size_t)n2 * RHD + (jj << 1));
            const unsigned int v3 =
                *reinterpret_cast<const unsigned int*>(mb + (size_t)n3 * RHD + (jj << 1));
            a0 = fmaf(w0, bfu(v0 & 0xffffu), a0);
            a1 = fmaf(w0, bfu(v0 >> 16), a1);
            a0 = fmaf(w1, bfu(v1 & 0xffffu), a0);
            a1 = fmaf(w1, bfu(v1 >> 16), a1);
            a0 = fmaf(w2, bfu(v2 & 0xffffu), a0);
            a1 = fmaf(w2, bfu(v2 >> 16), a1);
            a0 = fmaf(w3, bfu(v3 & 0xffffu), a0);
            a1 = fmaf(w3, bfu(v3 >> 16), a1);
        }
        for (; q < len; q += 8) {
            const float w0 = lal[q] * inv;
            const int   n0 = lnode[q];
            const unsigned int v0 =
                *reinterpret_cast<const unsigned int*>(mb + (size_t)n0 * RHD + (jj << 1));
            a0 = fmaf(w0, bfu(v0 & 0xffffu), a0);
            a1 = fmaf(w0, bfu(v0 >> 16), a1);
        }
    } else {
        float sum = 0.f;
        for (int i = tid; i < len; i += 512)
            sum += __int_as_float(side ? rc[i].w : rc[i].y);
#pragma unroll
        for (int off = 32; off > 0; off >>= 1) sum += __shfl_xor(sum, off);
        if ((tid & 63) == 0) red[slot] = sum;
        __syncthreads();
        sum = ((red[0] + red[1]) + (red[2] + red[3]))
            + ((red[4] + red[5]) + (red[6] + red[7]));
        const float inv = 1.f / sum;

        for (int c0 = 0; c0 < len; c0 += 512) {
            __syncthreads();
            int i = c0 + tid;
            if (i < len) {
                int4 v = rc[i];
                lnode[tid] = side ? v.z : v.x;
                lal[tid] = __int_as_float(side ? v.w : v.y) * inv;
            }
            __syncthreads();
            const int nc = min(512, len - c0);
            for (int q = slot; q < nc; q += 8) {
                const float wq = lal[q];
                const int n = lnode[q];
                const unsigned int v =
                    *reinterpret_cast<const unsigned int*>(mb + (size_t)n * RHD + (jj << 1));
                a0 = fmaf(wq, bfu(v & 0xffffu), a0);
                a1 = fmaf(wq, bfu(v >> 16), a1);
            }
        }
    }

    part[slot][(jj << 1) + 0] = a0;
    part[slot][(jj << 1) + 1] = a1;
    __syncthreads();
    if (tid < 128) {
        float v = ((part[0][tid] + part[1][tid]) + (part[2][tid] + part[3][tid]))
                + ((part[4][tid] + part[5][tid]) + (part[6][tid] + part[7][tid]));
        y[((size_t)side * R + r) * RHD + tid] = v;   // exclusive row: plain store
    }
}

// ---------------- tiny GEMM2 on [R,128]: out = y@(W+I) + gated bias ---------
__global__ __launch_bounds__(128) void k_out(
    const float* __restrict__ y,      // [2][R][128]
    const float* __restrict__ rhw, const float* __restrict__ rtw,  // [128][128]
    const float* __restrict__ rhb, const float* __restrict__ rtb,
    const int* __restrict__ starts,
    float* __restrict__ out, int R)
{
    const int r = blockIdx.x;
    const int j = threadIdx.x;
    __shared__ float ph[RHD], pt[RHD];
    ph[j] = y[(size_t)r * RHD + j];
    pt[j] = y[((size_t)R + r) * RHD + j];
    __syncthreads();
    float acc = ph[j] + pt[j];                      // residuals (0 if empty)
    if (starts[r + 1] > starts[r]) acc += rhb[j] + rtb[j];
    float a = 0.f;
#pragma unroll 8
    for (int k = 0; k < RHD; k++) {
        a = fmaf(ph[k], rhw[k * RHD + j], a);
        a = fmaf(pt[k], rtw[k * RHD + j], a);
    }
    out[(size_t)r * RHD + j] = acc + a;
}

// ---------------------------------------------------------------------------
extern "C" void kernel_launch(void* const* d_in, const int* in_sizes, int n_in,
                              void* d_out, int out_size, void* d_ws, size_t ws_size,
                              hipStream_t stream)
{
    const float* xe  = (const float*)d_in[0];
    const int*  eidx = (const int*)d_in[1];
    const int*  rel  = (const int*)d_in[2];
    const float* wh  = (const float*)d_in[4];
    const float* wt  = (const float*)d_in[5];
    const float* ah1 = (const float*)d_in[6];
    const float* ah2 = (const float*)d_in[7];
    const float* at1 = (const float*)d_in[8];
    const float* at2 = (const float*)d_in[9];
    const float* rhw = (const float*)d_in[10];
    const float* rhb = (const float*)d_in[11];
    const float* rtw = (const float*)d_in[12];
    const float* rtb = (const float*)d_in[13];
    float* out = (float*)d_out;

    const int N = in_sizes[0] / EHD;
    const int E = in_sizes[2];
    const int R = out_size / RHD;
    const int* eh = eidx;
    const int* et = eidx + E;

    char* ws = (char*)d_ws;
    size_t off = 0;
    auto alloc = [&](size_t bytes) -> void* {
        void* p = ws + off;
        off = (off + bytes + 255) & ~(size_t)255;
        return p;
    };
    short* xrh   = (short*)alloc((size_t)N * RHD * sizeof(short));
    short* xrt   = (short*)alloc((size_t)N * RHD * sizeof(short));
    short* whT   = (short*)alloc((size_t)RHD * EHD * sizeof(short));
    short* wtT   = (short*)alloc((size_t)RHD * EHD * sizeof(short));
    float* y     = (float*)alloc((size_t)2 * R * RHD * sizeof(float));
    float2* sA   = (float2*)alloc((size_t)N * sizeof(float2));
    float2* sB   = (float2*)alloc((size_t)N * sizeof(float2));
    int* counts  = (int*)alloc((size_t)R * sizeof(int));
    int* starts  = (int*)alloc((size_t)(R + 1) * sizeof(int));
    int* cursor  = (int*)alloc((size_t)R * sizeof(int));
    int* donecnt = (int*)alloc(sizeof(int));
    int4* rec    = (int4*)alloc((size_t)E * sizeof(int4));
    (void)ws_size; (void)n_in;

    hipMemsetAsync(counts, 0, (size_t)R * sizeof(int), stream);
    hipMemsetAsync(donecnt, 0, sizeof(int), stream);
    hipMemsetAsync(y, 0, (size_t)2 * R * RHD * sizeof(float), stream);

    k_prep2<<<dim3(EHD / 32, RHD / 32, 2), 256, 0, stream>>>(wh, wt, whT, wtT);

    k_fused<<<(N + 63) / 64, 256, 0, stream>>>(
        xe, whT, wtT, ah1, ah2, at1, at2,
        sA, sB, xrh, xrt, N, rel, counts, starts, cursor, donecnt, R, E);

    k_scatter<<<(E + SCHUNK - 1) / SCHUNK, 256, 0, stream>>>(
        rel, cursor, eh, et, sA, sB, rec, R, E);
    k_rel<<<dim3(R, 2), 512, 0, stream>>>(starts, rec, xrh, xrt, y, R);
    k_out<<<R, 128, 0, stream>>>(y, rhw, rtw, rhb, rtb, starts, out, R);
}

// Round 23
// 119.858 us; speedup vs baseline: 2.5943x; 2.5943x over previous
//
#include <hip/hip_runtime.h>
#include <hip/hip_bf16.h>
#include <math.h>

// ---------------------------------------------------------------------------
// GAT_E_to_R: N=100000, E=500000, EH=256, RH=128, R=1000
//   out[r] = y_h[r]@r_h_w + b_h + y_h[r] + y_t[r]@r_t_w + b_t + y_t[r],
//   y_s[r] = sum_e alpha_e * x_r_s[node_e]   (softmax weights sum to 1).
// k_fused: r21 champion (BM=64, gload_lds dbuf, Bs/Xs union, fused histogram;
// NO device fence — r22's fused scan regressed 4x via per-block threadfence).
// k_scatter: single int4 record (h,e1,t,e2), exp(logit) precomputed.
// k_rel: 512 thr / 8 slots, 4-deep gather ILP, no max pass.
// ---------------------------------------------------------------------------

#define EHD 256
#define RHD 128
#define RMAX 1024
#define HBLK 128    // blocks participating in fused histogram
#define SCHUNK 2048 // edges per scatter block
#define SEGMAX 4096 // max cached segment length in k_rel

typedef __attribute__((ext_vector_type(8))) short short8;
typedef __attribute__((ext_vector_type(4))) float f32x4;

__device__ __forceinline__ short f2bf(float x) {
    __hip_bfloat16 b = __float2bfloat16(x);   // RNE
    return *reinterpret_cast<short*>(&b);
}
__device__ __forceinline__ float bfu(unsigned int u) {
    return __uint_as_float(u << 16);
}
__device__ __forceinline__ float leaky(float x) { return x > 0.f ? x : 0.01f * x; }
// Xs swizzle: XOR 16B chunk index with row&7 (keeps short8 alignment)
__device__ __forceinline__ int xswz(int row, int col) {
    return col ^ ((row & 7) << 3);
}

// ---- transpose+convert both weight mats: dst[n][k] = src[k][n] (bf16) ------
__global__ __launch_bounds__(256) void k_prep2(const float* __restrict__ wh,
                                               const float* __restrict__ wt,
                                               short* __restrict__ whT,
                                               short* __restrict__ wtT)
{
    const float* src = blockIdx.z ? wt : wh;
    short* dst = blockIdx.z ? wtT : whT;
    __shared__ float t[32][33];
    const int k0 = blockIdx.x * 32, n0 = blockIdx.y * 32;
    const int tr = threadIdx.x >> 3, tc = (threadIdx.x & 7) << 2;
    float4 v = *reinterpret_cast<const float4*>(src + (size_t)(k0 + tr) * RHD + n0 + tc);
    t[tr][tc + 0] = v.x; t[tr][tc + 1] = v.y;
    t[tr][tc + 2] = v.z; t[tr][tc + 3] = v.w;
    __syncthreads();
    short* o = dst + (size_t)(n0 + tr) * EHD + k0 + tc;
    o[0] = f2bf(t[tc + 0][tr]); o[1] = f2bf(t[tc + 1][tr]);
    o[2] = f2bf(t[tc + 2][tr]); o[3] = f2bf(t[tc + 3][tr]);
}

// ---- fused: xr = xe@{wh,wt} (bf16 out); sA=(s1,s3), sB=(s2,s4); histogram ---
__global__ __launch_bounds__(256, 4) void k_fused(
    const float* __restrict__ xe,
    const short* __restrict__ whT, const short* __restrict__ wtT,   // [128][256]
    const float* __restrict__ ah1, const float* __restrict__ ah2,
    const float* __restrict__ at1, const float* __restrict__ at2,
    float2* __restrict__ sA, float2* __restrict__ sB,
    short* __restrict__ xrh, short* __restrict__ xrt, int N,
    const int* __restrict__ rel, int* __restrict__ counts, int R, int E)
{
    __shared__ __align__(16) union {
        short Bs[2][2][128][32];       // 32 KB — [buf][mat][row][k] (unpadded)
        short Xs[2][64][128];          // 32 KB — epilogue transpose (swizzled)
        int   Hs[RMAX];                //  4 KB — fused histogram (tail)
    } u;

    const int tid = threadIdx.x;
    const int w = tid >> 6, l = tid & 63;
    const int ln = l & 15, lk = l >> 4;
    const int m0 = blockIdx.x * 64;
    const int orow = (w << 4) + (lk << 2);

    f32x4 acch[8], acct[8];
#pragma unroll
    for (int c = 0; c < 8; c++) {
        acch[c] = (f32x4){0.f, 0.f, 0.f, 0.f};
        acct[c] = (f32x4){0.f, 0.f, 0.f, 0.f};
    }

    // -------- GEMM1: K=256, 8 k-steps --------
    const int arow = m0 + (w << 4) + ln;
    const int aclamp = min(arow, N - 1);
    const float* abase = xe + (size_t)aclamp * EHD + (lk << 3);
    short* BsFlat = &u.Bs[0][0][0][0];

    const int Rl = l >> 2, kc = l & 3;

    auto stage = [&](int buf, int kt) {
#pragma unroll
        for (int i = 0; i < 4; i++) {
            const int j = (w << 2) + i;            // 0..15 (uniform per wave)
            const int Rr = (j << 4) + Rl;          // 0..255
            const int mat = Rr >> 7, row = Rr & 127;
            const short* g = (mat ? wtT : whT) + (size_t)row * EHD + kt + (kc << 3);
            __builtin_amdgcn_global_load_lds(
                (const __attribute__((address_space(1))) void*)g,
                (__attribute__((address_space(3))) void*)(BsFlat + (buf << 13) + (j << 9)),
                16, 0, 0);
        }
    };

    float4 a0 = *reinterpret_cast<const float4*>(abase);
    float4 a1 = *reinterpret_cast<const float4*>(abase + 4);
    stage(0, 0);                       // prologue: fill buffer 0

#pragma unroll
    for (int s = 0; s < 8; s++) {
        const int kt = s << 5;
        __syncthreads();               // buf[s&1] staged (vmcnt drained) +
                                       // buf[(s+1)&1] reads from s-1 done
        if (s < 7) stage((s + 1) & 1, kt + 32);   // in flight over MFMA phase
        short8 af;
        af[0] = f2bf(a0.x); af[1] = f2bf(a0.y); af[2] = f2bf(a0.z); af[3] = f2bf(a0.w);
        af[4] = f2bf(a1.x); af[5] = f2bf(a1.y); af[6] = f2bf(a1.z); af[7] = f2bf(a1.w);
        if (s < 7) {                   // A reg-prefetch for next step
            a0 = *reinterpret_cast<const float4*>(abase + kt + 32);
            a1 = *reinterpret_cast<const float4*>(abase + kt + 36);
        }
        const int b = s & 1;
#pragma unroll
        for (int c = 0; c < 8; c++) {
            short8 bh = *reinterpret_cast<const short8*>(&u.Bs[b][0][(c << 4) + ln][lk << 3]);
            short8 bt = *reinterpret_cast<const short8*>(&u.Bs[b][1][(c << 4) + ln][lk << 3]);
            acch[c] = __builtin_amdgcn_mfma_f32_16x16x32_bf16(af, bh, acch[c], 0, 0, 0);
            acct[c] = __builtin_amdgcn_mfma_f32_16x16x32_bf16(af, bt, acct[c], 0, 0, 0);
        }
    }
    __syncthreads();   // all Bs reads done before Xs overwrites (union)

    // -------- epilogue: scalars from fp32 acc; xr -> LDS bf16 (swizzled) -----
    float p1[4] = {0,0,0,0}, p2[4] = {0,0,0,0}, p3[4] = {0,0,0,0}, p4[4] = {0,0,0,0};
#pragma unroll
    for (int c = 0; c < 8; c++) {
        const int col = (c << 4) + ln;
        const float wa1 = ah1[col], wa2 = ah2[col], wa3 = at1[col], wa4 = at2[col];
#pragma unroll
        for (int r = 0; r < 4; r++) {
            const float vh = acch[c][r], vt = acct[c][r];
            p1[r] = fmaf(vh, wa1, p1[r]);
            p3[r] = fmaf(vh, wa3, p3[r]);
            p2[r] = fmaf(vt, wa2, p2[r]);
            p4[r] = fmaf(vt, wa4, p4[r]);
            const int row = orow + r;
            const int cs = xswz(row, col);
            u.Xs[0][row][cs] = f2bf(vh);
            u.Xs[1][row][cs] = f2bf(vt);
        }
    }
#pragma unroll
    for (int off = 1; off < 16; off <<= 1) {
#pragma unroll
        for (int r = 0; r < 4; r++) {
            p1[r] += __shfl_xor(p1[r], off);
            p2[r] += __shfl_xor(p2[r], off);
            p3[r] += __shfl_xor(p3[r], off);
            p4[r] += __shfl_xor(p4[r], off);
        }
    }
    if (ln == 0) {
#pragma unroll
        for (int r = 0; r < 4; r++) {
            const int grow = m0 + orow + r;
            if (grow < N) {
                sA[grow] = make_float2(p1[r], p3[r]);
                sB[grow] = make_float2(p2[r], p4[r]);
            }
        }
    }
    __syncthreads();
    // coalesced short8 stores of x_r (2 mats x 64 rows x 16 chunks)
#pragma unroll
    for (int it = 0; it < 8; it++) {
        const int idx = tid + (it << 8);
        const int mat = idx >> 10;
        const int rem = idx & 1023;
        const int row = rem >> 4;
        const int ch  = rem & 15;
        const int grow = m0 + row;
        if (grow < N) {
            const int cs = (ch << 3) ^ ((row & 7) << 3);
            short8 v = *reinterpret_cast<const short8*>(&u.Xs[mat][row][cs]);
            short* dst = (mat ? xrt : xrh) + (size_t)grow * RHD + (ch << 3);
            *reinterpret_cast<short8*>(dst) = v;
        }
    }

    // -------- fused relation histogram (blocks 0..HBLK-1; pipes are idle) ----
    if (blockIdx.x < HBLK) {
        __syncthreads();               // Xs reads above complete; reuse union
        for (int i = tid; i < R; i += 256) u.Hs[i] = 0;
        __syncthreads();
        for (int e = blockIdx.x * 256 + tid; e < E; e += HBLK * 256)
            atomicAdd(&u.Hs[rel[e]], 1);
        __syncthreads();
        for (int i = tid; i < R; i += 256) {
            int v = u.Hs[i];
            if (v) atomicAdd(&counts[i], v);
        }
    }
}

__global__ __launch_bounds__(1024) void k_scan(
    const int* __restrict__ counts, int* __restrict__ starts,
    int* __restrict__ cursor, int R, int E)
{
    __shared__ int buf[2][1024];
    int t = threadIdx.x;
    int v = (t < R) ? counts[t] : 0;
    buf[0][t] = v;
    int cur = 0;
    for (int off = 1; off < 1024; off <<= 1) {
        __syncthreads();
        int x = buf[cur][t];
        if (t >= off) x += buf[cur][t - off];
        buf[cur ^ 1][t] = x;
        cur ^= 1;
    }
    __syncthreads();
    int incl = buf[cur][t];
    if (t < R) { starts[t] = incl - v; cursor[t] = incl - v; }
    if (t == 0) starts[R] = E;
}

// ---- block-privatized scatter into packed int4 records ----------------------
// rec[pos] = (h, exp(e1), t, exp(e2)) — one 16B store per edge.
__global__ __launch_bounds__(256) void k_scatter(
    const int* __restrict__ rel, int* __restrict__ cursor,
    const int* __restrict__ eh, const int* __restrict__ et,
    const float2* __restrict__ sA, const float2* __restrict__ sB,
    int4* __restrict__ rec, int R, int E)
{
    __shared__ int lcnt[RMAX];
    __shared__ int lbase[RMAX];
    const int tid = threadIdx.x;
    const int base = blockIdx.x * SCHUNK;
    const int nE = min(SCHUNK, E - base);
    for (int i = tid; i < R; i += 256) lcnt[i] = 0;
    __syncthreads();
    for (int i = tid; i < nE; i += 256) atomicAdd(&lcnt[rel[base + i]], 1);
    __syncthreads();
    for (int r = tid; r < R; r += 256) {
        int c = lcnt[r];
        lbase[r] = c ? atomicAdd(&cursor[r], c) : 0;
        lcnt[r] = 0;
    }
    __syncthreads();
    for (int i = tid; i < nE; i += 256) {
        const int e = base + i;
        const int r = rel[e];
        const int off = atomicAdd(&lcnt[r], 1);
        const int pos = lbase[r] + off;
        const int h = eh[e], t = et[e];
        const float2 va = sA[h];      // (s1[h], s3[h])
        const float2 vb = sB[t];      // (s2[t], s4[t])
        const float x1 = __expf(leaky(va.x + vb.x));   // bounded: |logit|<~10
        const float x2 = __expf(leaky(va.y + vb.y));
        rec[pos] = make_int4(h, __float_as_int(x1), t, __float_as_int(x2));
    }
}

// ---------------- per-(relation,side) normalize + weighted reduce into y ----
// records hold exp(logit); alpha = w / sum(w). 512 thr = 8 slots.
__global__ __launch_bounds__(512) void k_rel(
    const int* __restrict__ starts,
    const int4* __restrict__ rec,
    const short* __restrict__ xrh, const short* __restrict__ xrt,
    float* __restrict__ y, int R)   // y[2][R][128], pre-zeroed
{
    const int r = blockIdx.x;
    const int side = blockIdx.y;
    const int start = starts[r], end = starts[r + 1];
    const int len = end - start;
    if (len <= 0) return;                        // y pre-zeroed
    const int tid = threadIdx.x;
    const int4* __restrict__ rc = rec + start;
    const unsigned short* __restrict__ mb =
        reinterpret_cast<const unsigned short*>(side ? xrt : xrh);

    __shared__ float red[8];
    __shared__ int   lnode[SEGMAX];
    __shared__ float lal[SEGMAX];
    __shared__ float part[8][128];

    const int slot = tid >> 6;        // 0..7
    const int jj = tid & 63;
    float a0 = 0.f, a1 = 0.f;

    if (len <= SEGMAX) {
        float sum = 0.f;
        for (int i = tid; i < len; i += 512) {
            int4 v = rc[i];
            const int node = side ? v.z : v.x;
            const float x = __int_as_float(side ? v.w : v.y);
            lnode[i] = node;
            lal[i] = x;
            sum += x;
        }
#pragma unroll
        for (int off = 32; off > 0; off >>= 1) sum += __shfl_xor(sum, off);
        if ((tid & 63) == 0) red[slot] = sum;
        __syncthreads();
        sum = ((red[0] + red[1]) + (red[2] + red[3]))
            + ((red[4] + red[5]) + (red[6] + red[7]));
        const float inv = 1.f / sum;

        // accumulate: slot takes edges q = slot+8k; 4 gathers in flight
        int q = slot;
        for (; q + 24 < len; q += 32) {
            const float w0 = lal[q] * inv;       const int n0 = lnode[q];
            const float w1 = lal[q + 8] * inv;   const int n1 = lnode[q + 8];
            const float w2 = lal[q + 16] * inv;  const int n2 = lnode[q + 16];
            const float w3 = lal[q + 24] * inv;  const int n3 = lnode[q + 24];
            const unsigned int v0 =
                *reinterpret_cast<const unsigned int*>(mb + (size_t)n0 * RHD + (jj << 1));
            const unsigned int v1 =
                *reinterpret_cast<const unsigned int*>(mb + (size_t)n1 * RHD + (jj << 1));
            const unsigned int v2 =
                *reinterpret_cast<const unsigned int*>(mb + (size_t)n2 * RHD + (jj << 1));
            const unsigned int v3 =
                *reinterpret_cast<const unsigned int*>(mb + (size_t)n3 * RHD + (jj << 1));
            a0 = fmaf(w0, bfu(v0 & 0xffffu), a0);
            a1 = fmaf(w0, bfu(v0 >> 16), a1);
            a0 = fmaf(w1, bfu(v1 & 0xffffu), a0);
            a1 = fmaf(w1, bfu(v1 >> 16), a1);
            a0 = fmaf(w2, bfu(v2 & 0xffffu), a0);
            a1 = fmaf(w2, bfu(v2 >> 16), a1);
            a0 = fmaf(w3, bfu(v3 & 0xffffu), a0);
            a1 = fmaf(w3, bfu(v3 >> 16), a1);
        }
        for (; q < len; q += 8) {
            const float w0 = lal[q] * inv;
            const int   n0 = lnode[q];
            const unsigned int v0 =
                *reinterpret_cast<const unsigned int*>(mb + (size_t)n0 * RHD + (jj << 1));
            a0 = fmaf(w0, bfu(v0 & 0xffffu), a0);
            a1 = fmaf(w0, bfu(v0 >> 16), a1);
        }
    } else {
        float sum = 0.f;
        for (int i = tid; i < len; i += 512)
            sum += __int_as_float(side ? rc[i].w : rc[i].y);
#pragma unroll
        for (int off = 32; off > 0; off >>= 1) sum += __shfl_xor(sum, off);
        if ((tid & 63) == 0) red[slot] = sum;
        __syncthreads();
        sum = ((red[0] + red[1]) + (red[2] + red[3]))
            + ((red[4] + red[5]) + (red[6] + red[7]));
        const float inv = 1.f / sum;

        for (int c0 = 0; c0 < len; c0 += 512) {
            __syncthreads();
            int i = c0 + tid;
            if (i < len) {
                int4 v = rc[i];
                lnode[tid] = side ? v.z : v.x;
                lal[tid] = __int_as_float(side ? v.w : v.y) * inv;
            }
            __syncthreads();
            const int nc = min(512, len - c0);
            for (int q = slot; q < nc; q += 8) {
                const float wq = lal[q];
                const int n = lnode[q];
                const unsigned int v =
                    *reinterpret_cast<const unsigned int*>(mb + (size_t)n * RHD + (jj << 1));
                a0 = fmaf(wq, bfu(v & 0xffffu), a0);
                a1 = fmaf(wq, bfu(v >> 16), a1);
            }
        }
    }

    part[slot][(jj << 1) + 0] = a0;
    part[slot][(jj << 1) + 1] = a1;
    __syncthreads();
    if (tid < 128) {
        float v = ((part[0][tid] + part[1][tid]) + (part[2][tid] + part[3][tid]))
                + ((part[4][tid] + part[5][tid]) + (part[6][tid] + part[7][tid]));
        y[((size_t)side * R + r) * RHD + tid] = v;   // exclusive row: plain store
    }
}

// ---------------- tiny GEMM2 on [R,128]: out = y@(W+I) + gated bias ---------
__global__ __launch_bounds__(128) void k_out(
    const float* __restrict__ y,      // [2][R][128]
    const float* __restrict__ rhw, const float* __restrict__ rtw,  // [128][128]
    const float* __restrict__ rhb, const float* __restrict__ rtb,
    const int* __restrict__ starts,
    float* __restrict__ out, int R)
{
    const int r = blockIdx.x;
    const int j = threadIdx.x;
    __shared__ float ph[RHD], pt[RHD];
    ph[j] = y[(size_t)r * RHD + j];
    pt[j] = y[((size_t)R + r) * RHD + j];
    __syncthreads();
    float acc = ph[j] + pt[j];                      // residuals (0 if empty)
    if (starts[r + 1] > starts[r]) acc += rhb[j] + rtb[j];
    float a = 0.f;
#pragma unroll 8
    for (int k = 0; k < RHD; k++) {
        a = fmaf(ph[k], rhw[k * RHD + j], a);
        a = fmaf(pt[k], rtw[k * RHD + j], a);
    }
    out[(size_t)r * RHD + j] = acc + a;
}

// ---------------------------------------------------------------------------
extern "C" void kernel_launch(void* const* d_in, const int* in_sizes, int n_in,
                              void* d_out, int out_size, void* d_ws, size_t ws_size,
                              hipStream_t stream)
{
    const float* xe  = (const float*)d_in[0];
    const int*  eidx = (const int*)d_in[1];
    const int*  rel  = (const int*)d_in[2];
    const float* wh  = (const float*)d_in[4];
    const float* wt  = (const float*)d_in[5];
    const float* ah1 = (const float*)d_in[6];
    const float* ah2 = (const float*)d_in[7];
    const float* at1 = (const float*)d_in[8];
    const float* at2 = (const float*)d_in[9];
    const float* rhw = (const float*)d_in[10];
    const float* rhb = (const float*)d_in[11];
    const float* rtw = (const float*)d_in[12];
    const float* rtb = (const float*)d_in[13];
    float* out = (float*)d_out;

    const int N = in_sizes[0] / EHD;
    const int E = in_sizes[2];
    const int R = out_size / RHD;
    const int* eh = eidx;
    const int* et = eidx + E;

    char* ws = (char*)d_ws;
    size_t off = 0;
    auto alloc = [&](size_t bytes) -> void* {
        void* p = ws + off;
        off = (off + bytes + 255) & ~(size_t)255;
        return p;
    };
    short* xrh   = (short*)alloc((size_t)N * RHD * sizeof(short));
    short* xrt   = (short*)alloc((size_t)N * RHD * sizeof(short));
    short* whT   = (short*)alloc((size_t)RHD * EHD * sizeof(short));
    short* wtT   = (short*)alloc((size_t)RHD * EHD * sizeof(short));
    float* y     = (float*)alloc((size_t)2 * R * RHD * sizeof(float));
    float2* sA   = (float2*)alloc((size_t)N * sizeof(float2));
    float2* sB   = (float2*)alloc((size_t)N * sizeof(float2));
    int* counts  = (int*)alloc((size_t)R * sizeof(int));
    int* starts  = (int*)alloc((size_t)(R + 1) * sizeof(int));
    int* cursor  = (int*)alloc((size_t)R * sizeof(int));
    int4* rec    = (int4*)alloc((size_t)E * sizeof(int4));
    (void)ws_size; (void)n_in;

    hipMemsetAsync(counts, 0, (size_t)R * sizeof(int), stream);
    hipMemsetAsync(y, 0, (size_t)2 * R * RHD * sizeof(float), stream);

    k_prep2<<<dim3(EHD / 32, RHD / 32, 2), 256, 0, stream>>>(wh, wt, whT, wtT);

    k_fused<<<(N + 63) / 64, 256, 0, stream>>>(
        xe, whT, wtT, ah1, ah2, at1, at2,
        sA, sB, xrh, xrt, N, rel, counts, R, E);

    k_scan<<<1, 1024, 0, stream>>>(counts, starts, cursor, R, E);
    k_scatter<<<(E + SCHUNK - 1) / SCHUNK, 256, 0, stream>>>(
        rel, cursor, eh, et, sA, sB, rec, R, E);
    k_rel<<<dim3(R, 2), 512, 0, stream>>>(starts, rec, xrh, xrt, y, R);
    k_out<<<R, 128, 0, stream>>>(y, rhw, rtw, rhb, rtb, starts, out, R);
}